// Round 8
// baseline (346.056 us; speedup 1.0000x reference)
//
#include <hip/hip_runtime.h>
#include <math.h>

// HydraChannelMixer, MI355X (gfx950). Round 10: break cross-block phase-lock.
// Single delta vs R9 (116us steady fused): first-batch dispatch stagger.
// Evidence: 79% of block lifetime is stall, yet VALUBusy only 41% with 8
// waves/SIMD from 8 DIFFERENT blocks => stalls are correlated. Identical
// deterministic blocks start/finish/refill in lockstep, so every L2/HBM
// latency front + barrier coincides. Stagger slot (bp>>8, first 2048 blocks)
// by ~0.75us each (~one phase period / 8) to decorrelate; rolling refill
// inherits the stagger. Worst-case one-time cost ~5us.
// Shapes: B=64, C=21, P=96, D=256, R=32, H=64. One block per bp-row.

#define DD 256
#define CC 21
#define RR 32
#define HH 64
#define PP 96
#define BB 64
#define PD (PP * DD)
#define NBP (BB * PP)     // 6144
#define NT 256

#define HBS 264           // hbf row stride (shorts): 528B, multiple of 16B
#define LWS 40            // lowbf row stride (shorts): 80B, multiple of 16B

// d_ws layout (bytes) — identical to proven baseline
#define WS_WDB  0         // 8192 sh: Wd' bf16 frags, 16 tiles (kb*2+ni)*512
#define WS_W4B  16384     // 4096 sh: [Wq|Wk|Wv|Wg] bf16 frags, 8 tiles
#define WS_WUB  24576     // 8192 sh: Wu bf16 frags, 16 tiles
#define WS_DN1P 40960     // 16384 sh: dn1w^T packed bf16 [kb][j][8]
#define WS_DN2P 73728     // 16384 sh: dn2w packed bf16 [jb][d][8]
#define WS_S1   106496    // 32 f32: sum_k bf16(ln_w*Wd)[k][r]
#define WS_S2   106624    // 32 f32: ln_b@Wd + bd
#define WS_LG   106752    // 256 f32: channel_logits

typedef __attribute__((ext_vector_type(8))) short bf16x8;
typedef __attribute__((ext_vector_type(4))) float f32x4;
typedef __attribute__((ext_vector_type(4))) unsigned short u16x4;

__device__ __forceinline__ float gelu_exact(float x) {
    return 0.5f * x * (1.0f + erff(x * 0.70710678118654752440f));
}
__device__ __forceinline__ float sigmoidf_(float x) {
    return 1.0f / (1.0f + __expf(-x));
}
__device__ __forceinline__ short f2bf(float f) {            // RNE f32->bf16
    union { float f; unsigned u; } v; v.f = f;
    unsigned r = v.u + 0x7FFFu + ((v.u >> 16) & 1u);
    return (short)(unsigned short)(r >> 16);
}
__device__ __forceinline__ float bf2f_s(short s) {
    union { unsigned u; float f; } v; v.u = ((unsigned)(unsigned short)s) << 16;
    return v.f;
}

// DPP butterfly add: runs on VALU pipe (not LDS), ~2cyc issue each.
#define DPP_ADD(v, ctrl)                                                      \
    (v) += __builtin_bit_cast(float, __builtin_amdgcn_update_dpp(             \
               0, __builtin_bit_cast(int, (v)), (ctrl), 0xF, 0xF, true))

// all-lane sum over each contiguous 16-lane row: xor1, xor2, ror4, ror8
__device__ __forceinline__ float rowsum16(float v) {
    DPP_ADD(v, 0xB1);   // quad_perm(1,0,3,2) = xor1
    DPP_ADD(v, 0x4E);   // quad_perm(2,3,0,1) = xor2
    DPP_ADD(v, 0x124);  // row_ror:4
    DPP_ADD(v, 0x128);  // row_ror:8
    return v;
}
__device__ __forceinline__ float rdlane(float v, int l) {
    return __builtin_bit_cast(float,
        __builtin_amdgcn_readlane(__builtin_bit_cast(int, v), l));
}

// ---------------------------------------------------------------------------
// Preprocess (27 blocks) — IDENTICAL to proven baseline.
// MFMA frag layout (16x16x32): lane l holds elem[k=(l>>4)*8+j][idx16=l&15];
// this serves as A-frag (idx16=m) or B-frag (idx16=n) interchangeably.
// ---------------------------------------------------------------------------
extern "C" __global__ __launch_bounds__(NT)
void hydra_preproc(const float* __restrict__ ln_w, const float* __restrict__ ln_b,
                   const float* __restrict__ Wd,   const float* __restrict__ bd,
                   const float* __restrict__ Wq,   const float* __restrict__ Wk,
                   const float* __restrict__ Wv,   const float* __restrict__ Wg,
                   const float* __restrict__ Wu,
                   const float* __restrict__ cn1w, const float* __restrict__ cn1b,
                   const float* __restrict__ cn2w, const float* __restrict__ cn2b,
                   const float* __restrict__ dn1w, const float* __restrict__ dn2w,
                   short* __restrict__ WdB, short* __restrict__ W4B,
                   short* __restrict__ WuB, short* __restrict__ dn1P,
                   short* __restrict__ dn2P,
                   float* __restrict__ s1p, float* __restrict__ s2p,
                   float* __restrict__ logits)
{
    const int t = threadIdx.x, lane = t & 63, w = t >> 6, bid = blockIdx.x;
    const int q = lane >> 4, nl = lane & 15;

    if (bid < 4) {                       // WdB: 16 tiles, tile = kb*2 + ni
        int tile = bid * 4 + w;
        int kb = tile >> 1, ni = tile & 1;
        int kbase = kb * 32 + q * 8;
        int n = ni * 16 + nl;
        bf16x8 o;
        #pragma unroll
        for (int j = 0; j < 8; ++j) {
            int k = kbase + j;
            o[j] = f2bf(ln_w[k] * Wd[k * RR + n]);
        }
        *(bf16x8*)(WdB + tile * 512 + lane * 8) = o;
    } else if (bid < 6) {                // W4B: 8 tiles
        int ni = (bid - 4) * 4 + w;
        int n = ni * 16 + nl;
        const float* Wsel = (n < 32) ? Wq : (n < 64) ? Wk : (n < 96) ? Wv : Wg;
        int nn = n & 31;
        bf16x8 o;
        #pragma unroll
        for (int j = 0; j < 8; ++j) o[j] = f2bf(Wsel[(q * 8 + j) * RR + nn]);
        *(bf16x8*)(W4B + ni * 512 + lane * 8) = o;
    } else if (bid < 10) {               // WuB: 16 tiles
        int ni = (bid - 6) * 4 + w;
        int n = ni * 16 + nl;
        bf16x8 o;
        #pragma unroll
        for (int j = 0; j < 8; ++j) o[j] = f2bf(Wu[(q * 8 + j) * DD + n]);
        *(bf16x8*)(WuB + ni * 512 + lane * 8) = o;
    } else if (bid == 10) {              // s1, s2, channel logits
        __shared__ float red1[8][33], red2[8][33];
        __shared__ float clh[HH];
        int r = t & 31, ks = t >> 5;
        float a1 = 0.f, a2 = 0.f;
        for (int k = ks * 32; k < ks * 32 + 32; ++k) {
            float wv = Wd[k * RR + r];
            a1 += bf2f_s(f2bf(ln_w[k] * wv));   // match MFMA's bf16-rounded tile
            a2 += ln_b[k] * wv;
        }
        red1[ks][r] = a1; red2[ks][r] = a2;
        if (t < HH) {
            const float lc = 0.44073977f;       // log(21)/log(1000)
            clh[t] = gelu_exact(lc * cn1w[t] + cn1b[t]);
        }
        __syncthreads();
        if (t < RR) {
            float s1 = 0.f, s2 = 0.f;
            #pragma unroll
            for (int s = 0; s < 8; ++s) { s1 += red1[s][t]; s2 += red2[s][t]; }
            s1p[t] = s1;
            s2p[t] = s2 + bd[t];
        }
        float a = 0.f;
        #pragma unroll 8
        for (int j = 0; j < HH; ++j) a += clh[j] * cn2w[j * DD + t];
        logits[t] = a + cn2b[t];
    } else if (bid < 19) {               // dn1P: [kb][j][8], kb=0..31, j=0..63
        int slot = (bid - 11) * 256 + t; // 0..2047
        int kb = slot >> 6, j = slot & 63;
        bf16x8 o;
        #pragma unroll
        for (int ki = 0; ki < 8; ++ki) o[ki] = f2bf(dn1w[(kb * 8 + ki) * HH + j]);
        *(bf16x8*)(dn1P + slot * 8) = o;
    } else {                             // dn2P: [jb][d][8], jb=0..7, d=0..255
        int slot = (bid - 19) * 256 + t;
        int jb = slot >> 8, d = slot & 255;
        bf16x8 o;
        #pragma unroll
        for (int ji = 0; ji < 8; ++ji) o[ji] = f2bf(dn2w[(jb * 8 + ji) * DD + d]);
        *(bf16x8*)(dn2P + slot * 8) = o;
    }
}

// ---------------------------------------------------------------------------
// Main fused kernel: one block per bp-row, 256 threads (4 waves), 5 barriers.
// __launch_bounds__(256,8): 8 blocks/CU (32 waves).
// ---------------------------------------------------------------------------
extern "C" __global__ __launch_bounds__(NT, 8)
void hydra_fused(const float* __restrict__ x,
                 const float* __restrict__ bg,   const float* __restrict__ bu,
                 const float* __restrict__ dn1b, const float* __restrict__ dn2b,
                 const float* __restrict__ eps_p,
                 const short* __restrict__ WdB,  const short* __restrict__ W4B,
                 const short* __restrict__ WuB,  const short* __restrict__ dn1P,
                 const short* __restrict__ dn2P,
                 const float* __restrict__ s1p,  const float* __restrict__ s2p,
                 const float* __restrict__ logits,
                 float* __restrict__ out)
{
    __shared__ __align__(16) short  hbf[CC * HBS];    // 11,088 B  bf16 h tile
    __shared__ __align__(16) short  lowbf[32 * LWS];  //  2,560 B  [c][r] h_low -> M
    __shared__ __align__(16) float  sh_cv[DD];        //  1,024 B
    __shared__ __align__(16) float2 murs[32];         //    256 B  (mu, rs)
    __shared__ __align__(16) float  dn1p[128];        //    512 B  dn1 partials
    __shared__ __align__(16) float  sh_h1[HH];        //    256 B
    __shared__ __align__(16) float  gfp[64];          //    256 B  gf partials
    __shared__ __align__(16) float  sh_gf[RR];        //    128 B
    __shared__ __align__(16) float  sh_gate[DD];      //  1,024 B

    const int t    = threadIdx.x;
    const int lane = t & 63;
    const int w    = t >> 6;
    const int quad = lane >> 4;
    const int nl   = lane & 15;
    const int bp = blockIdx.x;
    const int b  = bp / PP;
    const int p  = bp - b * PP;
    const float* xbase = x   + (size_t)b * CC * PD + (size_t)p * DD;
    float*       obase = out + (size_t)b * CC * PD + (size_t)p * DD;

    // ---- Dispatch stagger: first batch (breadth-first slot = bp>>8) gets a
    //      slot-proportional delay (~0.75us/slot) to decorrelate the 8
    //      co-resident blocks' phase fronts. Rolling refill inherits it.
    if (bp < 2048) {
        int slot = bp >> 8;              // 0..7
        for (int i = 0; i < slot * 4; ++i) __builtin_amdgcn_s_sleep(7);
    }

    // ---- Phase 1: load h tile (wave w owns row iter*4+w), bf16 to LDS,
    //      LN stats per row via DPP butterflies. x is stream-once -> NT load.
    #pragma unroll
    for (int iter = 0; iter < 6; ++iter) {
        int c = iter * 4 + w;
        bool act = (c < CC);
        f32x4 v = {0.f, 0.f, 0.f, 0.f};
        if (act) v = __builtin_nontemporal_load(
                         (const f32x4*)(xbase + (size_t)c * PD + lane * 4));
        if (act) {
            u16x4 u;
            u[0] = (unsigned short)f2bf(v[0]); u[1] = (unsigned short)f2bf(v[1]);
            u[2] = (unsigned short)f2bf(v[2]); u[3] = (unsigned short)f2bf(v[3]);
            *(u16x4*)(hbf + c * HBS + lane * 4) = u;
        }
        float s  = v[0] + v[1] + v[2] + v[3];
        float s2 = v[0] * v[0] + v[1] * v[1] + v[2] * v[2] + v[3] * v[3];
        s  = rowsum16(s);
        s2 = rowsum16(s2);
        float tot  = rdlane(s, 0)  + rdlane(s, 16)  + rdlane(s, 32)  + rdlane(s, 48);
        float tot2 = rdlane(s2, 0) + rdlane(s2, 16) + rdlane(s2, 32) + rdlane(s2, 48);
        if (act && lane == 0) {
            float mu  = tot * (1.0f / DD);
            float var = tot2 * (1.0f / DD) - mu * mu;    // biased (LN)
            murs[c] = make_float2(mu, rsqrtf(var + 1e-5f));
        }
    }
    __syncthreads();   // B1

    // ---- Prefetch P3's weight frags (flight time covered by P2 + B2) -------
    bf16x8 pf0, pf1, pf2, pf3, pf4, pf5, pf6, pf7;
    {
        const short* src;
        if ((w & 1) == 0) {
            src = W4B + lane * 8;                       // 8 tiles, stride 512
        } else {
            const int half = w >> 1;
            src = dn1P + ((half * 16) * 64 + lane) * 8; // kb=half*16+0..7, stride 64*8
        }
        pf0 = *(const bf16x8*)(src + 0 * 512);
        pf1 = *(const bf16x8*)(src + 1 * 512);
        pf2 = *(const bf16x8*)(src + 2 * 512);
        pf3 = *(const bf16x8*)(src + 3 * 512);
        pf4 = *(const bf16x8*)(src + 4 * 512);
        pf5 = *(const bf16x8*)(src + 5 * 512);
        pf6 = *(const bf16x8*)(src + 6 * 512);
        pf7 = *(const bf16x8*)(src + 7 * 512);
    }

    // ---- Phase 2: channel variance (unbiased over C) + down-proj MFMA,
    //      operand-swapped: C[r][c] = (Wd')^T @ h^T, stored to lowbf[c][r] ---
    {
        float cs = 0.f, cs2 = 0.f;
        #pragma unroll
        for (int c = 0; c < CC; ++c) {
            float v = bf2f_s(hbf[c * HBS + t]);
            cs += v; cs2 = fmaf(v, v, cs2);
        }
        sh_cv[t] = (cs2 - cs * cs * (1.0f / CC)) * (1.0f / (CC - 1));
    }
    {   // wave w: r-tile mt = w&1, ct = w>>1
        const int mt = w & 1, ct = w >> 1;
        const int c  = ct * 16 + nl;
        const int c_rd = (c < CC) ? c : (CC - 1);    // cols>=21: clone ch 20
        const int r0 = mt * 16 + quad * 4;
        f32x4 acc = {0.f, 0.f, 0.f, 0.f};
        #pragma unroll
        for (int kb = 0; kb < 8; ++kb) {
            bf16x8 bh = *(const bf16x8*)(hbf + c_rd * HBS + kb * 32 + quad * 8);
            bf16x8 aw = *(const bf16x8*)(WdB + (kb * 2 + mt) * 512 + lane * 8);
            acc = __builtin_amdgcn_mfma_f32_16x16x32_bf16(aw, bh, acc, 0, 0, 0);
        }
        const float2 mr = murs[c_rd];
        const f32x4 s1v = *(const f32x4*)(s1p + r0);
        const f32x4 s2v = *(const f32x4*)(s2p + r0);
        u16x4 o;
        #pragma unroll
        for (int reg = 0; reg < 4; ++reg)
            o[reg] = (unsigned short)f2bf(
                mr.y * (acc[reg] - mr.x * s1v[reg]) + s2v[reg]);
        *(u16x4*)(lowbf + c * LWS + r0) = o;
    }
    __syncthreads();   // B2

    // ---- Phase 3: waves 0,2: QKVG MFMA (prefetched W4B) + norms + gate +
    //               KV pool; waves 1,3: dn1 (first 8 kb prefetched) ----------
    const int mi2 = w >> 1;
    float qg0[4], qg1[4];
    if ((w & 1) == 0) {
        const int m = mi2 * 16 + nl;
        bf16x8 a = *(const bf16x8*)(lowbf + m * LWS + quad * 8);
        f32x4 acc[8];
        {
            f32x4 z = {0.f, 0.f, 0.f, 0.f};
            acc[0] = __builtin_amdgcn_mfma_f32_16x16x32_bf16(a, pf0, z, 0, 0, 0);
            acc[1] = __builtin_amdgcn_mfma_f32_16x16x32_bf16(a, pf1, z, 0, 0, 0);
            acc[2] = __builtin_amdgcn_mfma_f32_16x16x32_bf16(a, pf2, z, 0, 0, 0);
            acc[3] = __builtin_amdgcn_mfma_f32_16x16x32_bf16(a, pf3, z, 0, 0, 0);
            acc[4] = __builtin_amdgcn_mfma_f32_16x16x32_bf16(a, pf4, z, 0, 0, 0);
            acc[5] = __builtin_amdgcn_mfma_f32_16x16x32_bf16(a, pf5, z, 0, 0, 0);
            acc[6] = __builtin_amdgcn_mfma_f32_16x16x32_bf16(a, pf6, z, 0, 0, 0);
            acc[7] = __builtin_amdgcn_mfma_f32_16x16x32_bf16(a, pf7, z, 0, 0, 0);
        }
        // tiles: 0,1=Q | 2,3=K | 4,5=V | 6,7=G ; lane cols nl and 16+nl
        const float bg0 = bg[nl], bg1 = bg[16 + nl];
        float kv0 = 0.f, kv1 = 0.f;
        #pragma unroll
        for (int reg = 0; reg < 4; ++reg) {
            float q0 = acc[0][reg], q1 = acc[1][reg];
            float k0 = acc[2][reg], k1 = acc[3][reg];
            float q2 = rowsum16(q0 * q0 + q1 * q1);      // sum over 32 cols
            float k2 = rowsum16(k0 * k0 + k1 * k1);
            float qi = 1.0f / fmaxf(sqrtf(q2), 1e-12f);
            float ki = 1.0f / fmaxf(sqrtf(k2), 1e-12f);
            float g0 = sigmoidf_(acc[6][reg] + bg0);
            float g1 = sigmoidf_(acc[7][reg] + bg1);
            qg0[reg] = q0 * qi * g0;
            qg1[reg] = q1 * qi * g1;
            int rowg = mi2 * 16 + quad * 4 + reg;
            float msk = (rowg < CC) ? 1.0f : 0.0f;
            kv0 += msk * (k0 * ki * acc[4][reg]);
            kv1 += msk * (k1 * ki * acc[5][reg]);
        }
        kv0 += __shfl_xor(kv0, 16); kv0 += __shfl_xor(kv0, 32);
        kv1 += __shfl_xor(kv1, 16); kv1 += __shfl_xor(kv1, 32);
        if (quad == 0) {
            gfp[mi2 * 32 + nl]      = kv0;
            gfp[mi2 * 32 + 16 + nl] = kv1;
        }
    } else {
        const int half = w >> 1;     // waves 1,3 split K over two halves
        float p0 = 0.f, p1 = 0.f;
        #pragma unroll
        for (int i = 0; i < 16; ++i) {
            int kb = half * 16 + i;
            bf16x8 wv;
            if      (i == 0) wv = pf0;
            else if (i == 1) wv = pf1;
            else if (i == 2) wv = pf2;
            else if (i == 3) wv = pf3;
            else if (i == 4) wv = pf4;
            else if (i == 5) wv = pf5;
            else if (i == 6) wv = pf6;
            else if (i == 7) wv = pf7;
            else wv = *(const bf16x8*)(dn1P + (kb * 64 + lane) * 8);
            f32x4 c0 = *(const f32x4*)(sh_cv + kb * 8);
            f32x4 c1 = *(const f32x4*)(sh_cv + kb * 8 + 4);
            p0 += bf2f_s(wv[0]) * c0[0] + bf2f_s(wv[1]) * c0[1]
                + bf2f_s(wv[2]) * c0[2] + bf2f_s(wv[3]) * c0[3];
            p1 += bf2f_s(wv[4]) * c1[0] + bf2f_s(wv[5]) * c1[1]
                + bf2f_s(wv[6]) * c1[2] + bf2f_s(wv[7]) * c1[3];
        }
        dn1p[half * 64 + lane] = p0 + p1;
    }
    __syncthreads();   // B3

    // ---- Phase 4: prefetch dn2 frags (covers B4 + P5 front), finalize ------
    bf16x8 pd0 = *(const bf16x8*)(dn2P + (0 * 256 + t) * 8);
    bf16x8 pd1 = *(const bf16x8*)(dn2P + (1 * 256 + t) * 8);
    bf16x8 pd2 = *(const bf16x8*)(dn2P + (2 * 256 + t) * 8);
    bf16x8 pd3 = *(const bf16x8*)(dn2P + (3 * 256 + t) * 8);
    bf16x8 pd4 = *(const bf16x8*)(dn2P + (4 * 256 + t) * 8);
    bf16x8 pd5 = *(const bf16x8*)(dn2P + (5 * 256 + t) * 8);
    bf16x8 pd6 = *(const bf16x8*)(dn2P + (6 * 256 + t) * 8);
    bf16x8 pd7 = *(const bf16x8*)(dn2P + (7 * 256 + t) * 8);
    if (t < HH) sh_h1[t] = gelu_exact(dn1p[t] + dn1p[64 + t] + dn1b[t]);
    if (t < RR) sh_gf[t] = gfp[t] + gfp[32 + t];
    __syncthreads();   // B4

    // ---- Phase 5: adaptive gate (dn2, prefetched) + write M ----------------
    {
        const float eps = eps_p[0];
        float a0 = 0.f, a1 = 0.f;
        #pragma unroll
        for (int jb = 0; jb < 8; ++jb) {
            bf16x8 wv;
            if      (jb == 0) wv = pd0;
            else if (jb == 1) wv = pd1;
            else if (jb == 2) wv = pd2;
            else if (jb == 3) wv = pd3;
            else if (jb == 4) wv = pd4;
            else if (jb == 5) wv = pd5;
            else if (jb == 6) wv = pd6;
            else              wv = pd7;
            f32x4 h0 = *(const f32x4*)(sh_h1 + jb * 8);
            f32x4 h1 = *(const f32x4*)(sh_h1 + jb * 8 + 4);
            a0 += bf2f_s(wv[0]) * h0[0] + bf2f_s(wv[1]) * h0[1]
                + bf2f_s(wv[2]) * h0[2] + bf2f_s(wv[3]) * h0[3];
            a1 += bf2f_s(wv[4]) * h1[0] + bf2f_s(wv[5]) * h1[1]
                + bf2f_s(wv[6]) * h1[2] + bf2f_s(wv[7]) * h1[3];
        }
        sh_gate[t] = sigmoidf_(logits[t] + eps * (a0 + a1 + dn2b[t]));
    }
    if ((w & 1) == 0) {              // M = (Qn*gate_c)*gf, to lowbf[c][r]
        float gf0 = sh_gf[nl], gf1 = sh_gf[16 + nl];
        #pragma unroll
        for (int reg = 0; reg < 4; ++reg) {
            int rowg = mi2 * 16 + quad * 4 + reg;
            lowbf[rowg * LWS + nl]      = f2bf(qg0[reg] * gf0);
            lowbf[rowg * LWS + 16 + nl] = f2bf(qg1[reg] * gf1);
        }
    }
    // Prefetch WuB frags for P6 (flight covered by B5)
    bf16x8 pw0 = *(const bf16x8*)(WuB + (w * 4 + 0) * 512 + lane * 8);
    bf16x8 pw1 = *(const bf16x8*)(WuB + (w * 4 + 1) * 512 + lane * 8);
    bf16x8 pw2 = *(const bf16x8*)(WuB + (w * 4 + 2) * 512 + lane * 8);
    bf16x8 pw3 = *(const bf16x8*)(WuB + (w * 4 + 3) * 512 + lane * 8);
    __syncthreads();   // B5

    // ---- Phase 6: up-proj operand-swapped: C[d][c] = Wu^T @ M^T ------------
    // wave w owns d-tiles w*4..w*4+3, both c-tiles; reg axis = 4 consecutive d
    {
        bf16x8 bf0 = *(const bf16x8*)(lowbf + nl * LWS + quad * 8);        // c=nl
        bf16x8 bf1 = *(const bf16x8*)(lowbf + (16 + nl) * LWS + quad * 8); // c=16+nl
        const int c0 = nl, c1 = 16 + nl;
        #pragma unroll
        for (int i = 0; i < 4; ++i) {
            const int dt = w * 4 + i;
            bf16x8 af;
            if      (i == 0) af = pw0;
            else if (i == 1) af = pw1;
            else if (i == 2) af = pw2;
            else             af = pw3;
            f32x4 z = {0.f, 0.f, 0.f, 0.f};
            f32x4 a0 = __builtin_amdgcn_mfma_f32_16x16x32_bf16(af, bf0, z, 0, 0, 0);
            f32x4 a1 = __builtin_amdgcn_mfma_f32_16x16x32_bf16(af, bf1, z, 0, 0, 0);
            const int db = dt * 16 + quad * 4;
            const f32x4 gd  = *(const f32x4*)(sh_gate + db);
            const f32x4 bud = *(const f32x4*)(bu + db);
            {
                u16x4 h4 = *(const u16x4*)(hbf + c0 * HBS + db);
                f32x4 o;
                #pragma unroll
                for (int reg = 0; reg < 4; ++reg)
                    o[reg] = fmaf(gd[reg], a0[reg] + bud[reg],
                                  bf2f_s((short)h4[reg]));
                __builtin_nontemporal_store(o, (f32x4*)(obase + (size_t)c0 * PD + db));
            }
            if (nl < CC - 16) {      // c1 < 21
                u16x4 h4 = *(const u16x4*)(hbf + c1 * HBS + db);
                f32x4 o;
                #pragma unroll
                for (int reg = 0; reg < 4; ++reg)
                    o[reg] = fmaf(gd[reg], a1[reg] + bud[reg],
                                  bf2f_s((short)h4[reg]));
                __builtin_nontemporal_store(o, (f32x4*)(obase + (size_t)c1 * PD + db));
            }
        }
    }
}

extern "C" void kernel_launch(void* const* d_in, const int* in_sizes, int n_in,
                              void* d_out, int out_size, void* d_ws, size_t ws_size,
                              hipStream_t stream) {
    const float* x    = (const float*)d_in[0];
    const float* ln_w = (const float*)d_in[1];
    const float* ln_b = (const float*)d_in[2];
    const float* Wd   = (const float*)d_in[3];
    const float* bd   = (const float*)d_in[4];
    const float* Wq   = (const float*)d_in[5];
    const float* Wk   = (const float*)d_in[6];
    const float* Wv   = (const float*)d_in[7];
    const float* Wg   = (const float*)d_in[8];
    const float* bg   = (const float*)d_in[9];
    const float* Wu   = (const float*)d_in[10];
    const float* bu   = (const float*)d_in[11];
    const float* cn1w = (const float*)d_in[12];
    const float* cn1b = (const float*)d_in[13];
    const float* cn2w = (const float*)d_in[14];
    const float* cn2b = (const float*)d_in[15];
    const float* dn1w = (const float*)d_in[16];
    const float* dn1b = (const float*)d_in[17];
    const float* dn2w = (const float*)d_in[18];
    const float* dn2b = (const float*)d_in[19];
    const float* eps  = (const float*)d_in[20];
    float* out = (float*)d_out;

    char* ws = (char*)d_ws;
    short* WdB  = (short*)(ws + WS_WDB);
    short* W4B  = (short*)(ws + WS_W4B);
    short* WuB  = (short*)(ws + WS_WUB);
    short* dn1P = (short*)(ws + WS_DN1P);
    short* dn2P = (short*)(ws + WS_DN2P);
    float* s1p  = (float*)(ws + WS_S1);
    float* s2p  = (float*)(ws + WS_S2);
    float* lg   = (float*)(ws + WS_LG);

    hydra_preproc<<<27, NT, 0, stream>>>(ln_w, ln_b, Wd, bd, Wq, Wk, Wv, Wg, Wu,
                                         cn1w, cn1b, cn2w, cn2b, dn1w, dn2w,
                                         WdB, W4B, WuB, dn1P, dn2P, s1p, s2p, lg);
    hydra_fused<<<NBP, NT, 0, stream>>>(x, bg, bu, dn1b, dn2b, eps,
                                        WdB, W4B, WuB, dn1P, dn2P, s1p, s2p, lg,
                                        out);
}

// Round 9
// 340.450 us; speedup vs baseline: 1.0165x; 1.0165x over previous
//
#include <hip/hip_runtime.h>
#include <math.h>

// HydraChannelMixer, MI355X (gfx950). Round 11: forced memory-level parallelism.
// R10 stagger = NULL (116us, identical counters) -> phase-lock refuted.
// Key evidence: VGPR_Count=32 under (NT,8) => compiler serialized every
// multi-load sequence (P1 6x x-loads, P3 8x W4B, dn1 16x L2 loads...) and
// sank all R9 "prefetches" to use sites. Fix: within each phase, issue the
// load GROUP, then asm use-pin (forces co-issue + single overlapped latency),
// then consume. Groups sized for peak VGPR <= ~60 (cap 64 at 8 blk/CU).
// Also: stagger removed, NT stores reverted (raised WRITE 170->196MB),
// NT x-loads kept (FETCH 77->70MB).
// Shapes: B=64, C=21, P=96, D=256, R=32, H=64. One block per bp-row.

#define DD 256
#define CC 21
#define RR 32
#define HH 64
#define PP 96
#define BB 64
#define PD (PP * DD)
#define NBP (BB * PP)     // 6144
#define NT 256

#define HBS 264           // hbf row stride (shorts): 528B, multiple of 16B
#define LWS 40            // lowbf row stride (shorts): 80B, multiple of 16B

// d_ws layout (bytes) — identical to proven baseline
#define WS_WDB  0         // 8192 sh: Wd' bf16 frags, 16 tiles (kb*2+ni)*512
#define WS_W4B  16384     // 4096 sh: [Wq|Wk|Wv|Wg] bf16 frags, 8 tiles
#define WS_WUB  24576     // 8192 sh: Wu bf16 frags, 16 tiles
#define WS_DN1P 40960     // 16384 sh: dn1w^T packed bf16 [kb][j][8]
#define WS_DN2P 73728     // 16384 sh: dn2w packed bf16 [jb][d][8]
#define WS_S1   106496    // 32 f32: sum_k bf16(ln_w*Wd)[k][r]
#define WS_S2   106624    // 32 f32: ln_b@Wd + bd
#define WS_LG   106752    // 256 f32: channel_logits

typedef __attribute__((ext_vector_type(8))) short bf16x8;
typedef __attribute__((ext_vector_type(4))) float f32x4;
typedef __attribute__((ext_vector_type(4))) unsigned short u16x4;

__device__ __forceinline__ float gelu_exact(float x) {
    return 0.5f * x * (1.0f + erff(x * 0.70710678118654752440f));
}
__device__ __forceinline__ float sigmoidf_(float x) {
    return 1.0f / (1.0f + __expf(-x));
}
__device__ __forceinline__ short f2bf(float f) {            // RNE f32->bf16
    union { float f; unsigned u; } v; v.f = f;
    unsigned r = v.u + 0x7FFFu + ((v.u >> 16) & 1u);
    return (short)(unsigned short)(r >> 16);
}
__device__ __forceinline__ float bf2f_s(short s) {
    union { unsigned u; float f; } v; v.u = ((unsigned)(unsigned short)s) << 16;
    return v.f;
}

// DPP butterfly add: runs on VALU pipe (not LDS), ~2cyc issue each.
#define DPP_ADD(v, ctrl)                                                      \
    (v) += __builtin_bit_cast(float, __builtin_amdgcn_update_dpp(             \
               0, __builtin_bit_cast(int, (v)), (ctrl), 0xF, 0xF, true))

// all-lane sum over each contiguous 16-lane row: xor1, xor2, ror4, ror8
__device__ __forceinline__ float rowsum16(float v) {
    DPP_ADD(v, 0xB1);   // quad_perm(1,0,3,2) = xor1
    DPP_ADD(v, 0x4E);   // quad_perm(2,3,0,1) = xor2
    DPP_ADD(v, 0x124);  // row_ror:4
    DPP_ADD(v, 0x128);  // row_ror:8
    return v;
}
__device__ __forceinline__ float rdlane(float v, int l) {
    return __builtin_bit_cast(float,
        __builtin_amdgcn_readlane(__builtin_bit_cast(int, v), l));
}

// use-pin: forces the listed values to be materialized (loads issued AND
// completed) at this point — one overlapped latency for the whole group.
#define PIN4(a,b,c,d)        asm volatile("" :: "v"(a), "v"(b), "v"(c), "v"(d))
#define PIN6(a,b,c,d,e,f)    asm volatile("" :: "v"(a), "v"(b), "v"(c), "v"(d), "v"(e), "v"(f))
#define PIN8(a,b,c,d,e,f,g,h) asm volatile("" :: "v"(a), "v"(b), "v"(c), "v"(d), "v"(e), "v"(f), "v"(g), "v"(h))

// ---------------------------------------------------------------------------
// Preprocess (27 blocks) — IDENTICAL to proven baseline.
// MFMA frag layout (16x16x32): lane l holds elem[k=(l>>4)*8+j][idx16=l&15];
// this serves as A-frag (idx16=m) or B-frag (idx16=n) interchangeably.
// ---------------------------------------------------------------------------
extern "C" __global__ __launch_bounds__(NT)
void hydra_preproc(const float* __restrict__ ln_w, const float* __restrict__ ln_b,
                   const float* __restrict__ Wd,   const float* __restrict__ bd,
                   const float* __restrict__ Wq,   const float* __restrict__ Wk,
                   const float* __restrict__ Wv,   const float* __restrict__ Wg,
                   const float* __restrict__ Wu,
                   const float* __restrict__ cn1w, const float* __restrict__ cn1b,
                   const float* __restrict__ cn2w, const float* __restrict__ cn2b,
                   const float* __restrict__ dn1w, const float* __restrict__ dn2w,
                   short* __restrict__ WdB, short* __restrict__ W4B,
                   short* __restrict__ WuB, short* __restrict__ dn1P,
                   short* __restrict__ dn2P,
                   float* __restrict__ s1p, float* __restrict__ s2p,
                   float* __restrict__ logits)
{
    const int t = threadIdx.x, lane = t & 63, w = t >> 6, bid = blockIdx.x;
    const int q = lane >> 4, nl = lane & 15;

    if (bid < 4) {                       // WdB: 16 tiles, tile = kb*2 + ni
        int tile = bid * 4 + w;
        int kb = tile >> 1, ni = tile & 1;
        int kbase = kb * 32 + q * 8;
        int n = ni * 16 + nl;
        bf16x8 o;
        #pragma unroll
        for (int j = 0; j < 8; ++j) {
            int k = kbase + j;
            o[j] = f2bf(ln_w[k] * Wd[k * RR + n]);
        }
        *(bf16x8*)(WdB + tile * 512 + lane * 8) = o;
    } else if (bid < 6) {                // W4B: 8 tiles
        int ni = (bid - 4) * 4 + w;
        int n = ni * 16 + nl;
        const float* Wsel = (n < 32) ? Wq : (n < 64) ? Wk : (n < 96) ? Wv : Wg;
        int nn = n & 31;
        bf16x8 o;
        #pragma unroll
        for (int j = 0; j < 8; ++j) o[j] = f2bf(Wsel[(q * 8 + j) * RR + nn]);
        *(bf16x8*)(W4B + ni * 512 + lane * 8) = o;
    } else if (bid < 10) {               // WuB: 16 tiles
        int ni = (bid - 6) * 4 + w;
        int n = ni * 16 + nl;
        bf16x8 o;
        #pragma unroll
        for (int j = 0; j < 8; ++j) o[j] = f2bf(Wu[(q * 8 + j) * DD + n]);
        *(bf16x8*)(WuB + ni * 512 + lane * 8) = o;
    } else if (bid == 10) {              // s1, s2, channel logits
        __shared__ float red1[8][33], red2[8][33];
        __shared__ float clh[HH];
        int r = t & 31, ks = t >> 5;
        float a1 = 0.f, a2 = 0.f;
        for (int k = ks * 32; k < ks * 32 + 32; ++k) {
            float wv = Wd[k * RR + r];
            a1 += bf2f_s(f2bf(ln_w[k] * wv));   // match MFMA's bf16-rounded tile
            a2 += ln_b[k] * wv;
        }
        red1[ks][r] = a1; red2[ks][r] = a2;
        if (t < HH) {
            const float lc = 0.44073977f;       // log(21)/log(1000)
            clh[t] = gelu_exact(lc * cn1w[t] + cn1b[t]);
        }
        __syncthreads();
        if (t < RR) {
            float s1 = 0.f, s2 = 0.f;
            #pragma unroll
            for (int s = 0; s < 8; ++s) { s1 += red1[s][t]; s2 += red2[s][t]; }
            s1p[t] = s1;
            s2p[t] = s2 + bd[t];
        }
        float a = 0.f;
        #pragma unroll 8
        for (int j = 0; j < HH; ++j) a += clh[j] * cn2w[j * DD + t];
        logits[t] = a + cn2b[t];
    } else if (bid < 19) {               // dn1P: [kb][j][8], kb=0..31, j=0..63
        int slot = (bid - 11) * 256 + t; // 0..2047
        int kb = slot >> 6, j = slot & 63;
        bf16x8 o;
        #pragma unroll
        for (int ki = 0; ki < 8; ++ki) o[ki] = f2bf(dn1w[(kb * 8 + ki) * HH + j]);
        *(bf16x8*)(dn1P + slot * 8) = o;
    } else {                             // dn2P: [jb][d][8], jb=0..7, d=0..255
        int slot = (bid - 19) * 256 + t;
        int jb = slot >> 8, d = slot & 255;
        bf16x8 o;
        #pragma unroll
        for (int ji = 0; ji < 8; ++ji) o[ji] = f2bf(dn2w[(jb * 8 + ji) * DD + d]);
        *(bf16x8*)(dn2P + slot * 8) = o;
    }
}

// ---------------------------------------------------------------------------
// Main fused kernel: one block per bp-row, 256 threads (4 waves), 5 barriers.
// __launch_bounds__(256,8): 8 blocks/CU (32 waves).
// ---------------------------------------------------------------------------
extern "C" __global__ __launch_bounds__(NT, 8)
void hydra_fused(const float* __restrict__ x,
                 const float* __restrict__ bg,   const float* __restrict__ bu,
                 const float* __restrict__ dn1b, const float* __restrict__ dn2b,
                 const float* __restrict__ eps_p,
                 const short* __restrict__ WdB,  const short* __restrict__ W4B,
                 const short* __restrict__ WuB,  const short* __restrict__ dn1P,
                 const short* __restrict__ dn2P,
                 const float* __restrict__ s1p,  const float* __restrict__ s2p,
                 const float* __restrict__ logits,
                 float* __restrict__ out)
{
    __shared__ __align__(16) short  hbf[CC * HBS];    // 11,088 B  bf16 h tile
    __shared__ __align__(16) short  lowbf[32 * LWS];  //  2,560 B  [c][r] h_low -> M
    __shared__ __align__(16) float  sh_cv[DD];        //  1,024 B
    __shared__ __align__(16) float2 murs[32];         //    256 B  (mu, rs)
    __shared__ __align__(16) float  dn1p[128];        //    512 B  dn1 partials
    __shared__ __align__(16) float  sh_h1[HH];        //    256 B
    __shared__ __align__(16) float  gfp[64];          //    256 B  gf partials
    __shared__ __align__(16) float  sh_gf[RR];        //    128 B
    __shared__ __align__(16) float  sh_gate[DD];      //  1,024 B

    const int t    = threadIdx.x;
    const int lane = t & 63;
    const int w    = t >> 6;
    const int quad = lane >> 4;
    const int nl   = lane & 15;
    const int bp = blockIdx.x;
    const int b  = bp / PP;
    const int p  = bp - b * PP;
    const float* xbase = x   + (size_t)b * CC * PD + (size_t)p * DD;
    float*       obase = out + (size_t)b * CC * PD + (size_t)p * DD;

    // ---- Phase 1: issue ALL 6 x-loads (NT), pin, then consume --------------
    {
        f32x4 x0 = {0.f,0.f,0.f,0.f}, x1 = x0, x2 = x0, x3 = x0, x4 = x0, x5 = x0;
        const bool a0 = (0*4 + w) < CC, a1 = (1*4 + w) < CC, a2 = (2*4 + w) < CC;
        const bool a3 = (3*4 + w) < CC, a4 = (4*4 + w) < CC, a5 = (5*4 + w) < CC;
        const float* xp = xbase + lane * 4;
        if (a0) x0 = __builtin_nontemporal_load((const f32x4*)(xp + (size_t)(0*4 + w) * PD));
        if (a1) x1 = __builtin_nontemporal_load((const f32x4*)(xp + (size_t)(1*4 + w) * PD));
        if (a2) x2 = __builtin_nontemporal_load((const f32x4*)(xp + (size_t)(2*4 + w) * PD));
        if (a3) x3 = __builtin_nontemporal_load((const f32x4*)(xp + (size_t)(3*4 + w) * PD));
        if (a4) x4 = __builtin_nontemporal_load((const f32x4*)(xp + (size_t)(4*4 + w) * PD));
        if (a5) x5 = __builtin_nontemporal_load((const f32x4*)(xp + (size_t)(5*4 + w) * PD));
        PIN6(x0, x1, x2, x3, x4, x5);

        #define P1_ROW(V, ACT, ITER)                                          \
        {                                                                     \
            const int c = (ITER) * 4 + w;                                     \
            if (ACT) {                                                        \
                u16x4 u;                                                      \
                u[0] = (unsigned short)f2bf((V)[0]);                          \
                u[1] = (unsigned short)f2bf((V)[1]);                          \
                u[2] = (unsigned short)f2bf((V)[2]);                          \
                u[3] = (unsigned short)f2bf((V)[3]);                          \
                *(u16x4*)(hbf + c * HBS + lane * 4) = u;                      \
            }                                                                 \
            float s  = (V)[0] + (V)[1] + (V)[2] + (V)[3];                     \
            float s2 = (V)[0]*(V)[0] + (V)[1]*(V)[1] + (V)[2]*(V)[2] + (V)[3]*(V)[3]; \
            s  = rowsum16(s);                                                 \
            s2 = rowsum16(s2);                                                \
            float tot  = rdlane(s,0)  + rdlane(s,16)  + rdlane(s,32)  + rdlane(s,48);  \
            float tot2 = rdlane(s2,0) + rdlane(s2,16) + rdlane(s2,32) + rdlane(s2,48); \
            if ((ACT) && lane == 0) {                                         \
                float mu  = tot * (1.0f / DD);                                \
                float var = tot2 * (1.0f / DD) - mu * mu;                     \
                murs[c] = make_float2(mu, rsqrtf(var + 1e-5f));               \
            }                                                                 \
        }
        P1_ROW(x0, a0, 0) P1_ROW(x1, a1, 1) P1_ROW(x2, a2, 2)
        P1_ROW(x3, a3, 3) P1_ROW(x4, a4, 4) P1_ROW(x5, a5, 5)
        #undef P1_ROW
    }
    __syncthreads();   // B1

    // ---- Phase 2: channel variance + down-proj MFMA (WdB group-loaded) -----
    {
        float cs = 0.f, cs2 = 0.f;
        #pragma unroll
        for (int c = 0; c < CC; ++c) {
            float v = bf2f_s(hbf[c * HBS + t]);
            cs += v; cs2 = fmaf(v, v, cs2);
        }
        sh_cv[t] = (cs2 - cs * cs * (1.0f / CC)) * (1.0f / (CC - 1));
    }
    {   // wave w: r-tile mt = w&1, ct = w>>1; out lowbf[c][r]
        const int mt = w & 1, ct = w >> 1;
        const int c  = ct * 16 + nl;
        const int c_rd = (c < CC) ? c : (CC - 1);    // cols>=21: clone ch 20
        const int r0 = mt * 16 + quad * 4;
        const short* wdp = WdB + mt * 512 + lane * 8;
        bf16x8 aw0 = *(const bf16x8*)(wdp + 0 * 1024);
        bf16x8 aw1 = *(const bf16x8*)(wdp + 1 * 1024);
        bf16x8 aw2 = *(const bf16x8*)(wdp + 2 * 1024);
        bf16x8 aw3 = *(const bf16x8*)(wdp + 3 * 1024);
        bf16x8 aw4 = *(const bf16x8*)(wdp + 4 * 1024);
        bf16x8 aw5 = *(const bf16x8*)(wdp + 5 * 1024);
        bf16x8 aw6 = *(const bf16x8*)(wdp + 6 * 1024);
        bf16x8 aw7 = *(const bf16x8*)(wdp + 7 * 1024);
        PIN8(aw0, aw1, aw2, aw3, aw4, aw5, aw6, aw7);
        const short* hrow = hbf + c_rd * HBS + quad * 8;
        f32x4 acc = {0.f, 0.f, 0.f, 0.f};
        acc = __builtin_amdgcn_mfma_f32_16x16x32_bf16(aw0, *(const bf16x8*)(hrow + 0*32), acc, 0, 0, 0);
        acc = __builtin_amdgcn_mfma_f32_16x16x32_bf16(aw1, *(const bf16x8*)(hrow + 1*32), acc, 0, 0, 0);
        acc = __builtin_amdgcn_mfma_f32_16x16x32_bf16(aw2, *(const bf16x8*)(hrow + 2*32), acc, 0, 0, 0);
        acc = __builtin_amdgcn_mfma_f32_16x16x32_bf16(aw3, *(const bf16x8*)(hrow + 3*32), acc, 0, 0, 0);
        acc = __builtin_amdgcn_mfma_f32_16x16x32_bf16(aw4, *(const bf16x8*)(hrow + 4*32), acc, 0, 0, 0);
        acc = __builtin_amdgcn_mfma_f32_16x16x32_bf16(aw5, *(const bf16x8*)(hrow + 5*32), acc, 0, 0, 0);
        acc = __builtin_amdgcn_mfma_f32_16x16x32_bf16(aw6, *(const bf16x8*)(hrow + 6*32), acc, 0, 0, 0);
        acc = __builtin_amdgcn_mfma_f32_16x16x32_bf16(aw7, *(const bf16x8*)(hrow + 7*32), acc, 0, 0, 0);
        const float2 mr = murs[c_rd];
        const f32x4 s1v = *(const f32x4*)(s1p + r0);
        const f32x4 s2v = *(const f32x4*)(s2p + r0);
        u16x4 o;
        #pragma unroll
        for (int reg = 0; reg < 4; ++reg)
            o[reg] = (unsigned short)f2bf(
                mr.y * (acc[reg] - mr.x * s1v[reg]) + s2v[reg]);
        *(u16x4*)(lowbf + c * LWS + r0) = o;
    }
    __syncthreads();   // B2

    // ---- Phase 3: waves 0,2: QKVG MFMA (W4B 2x4 group) + norms + gate +
    //               KV pool; waves 1,3: dn1 (2x8 group-loaded) ---------------
    const int mi2 = w >> 1;
    float qg0[4], qg1[4];
    if ((w & 1) == 0) {
        const int m = mi2 * 16 + nl;
        bf16x8 a = *(const bf16x8*)(lowbf + m * LWS + quad * 8);
        const short* w4p = W4B + lane * 8;
        f32x4 acc[8];
        {
            bf16x8 b0 = *(const bf16x8*)(w4p + 0 * 512);
            bf16x8 b1 = *(const bf16x8*)(w4p + 1 * 512);
            bf16x8 b2 = *(const bf16x8*)(w4p + 2 * 512);
            bf16x8 b3 = *(const bf16x8*)(w4p + 3 * 512);
            PIN4(b0, b1, b2, b3);
            f32x4 z = {0.f, 0.f, 0.f, 0.f};
            acc[0] = __builtin_amdgcn_mfma_f32_16x16x32_bf16(a, b0, z, 0, 0, 0);
            acc[1] = __builtin_amdgcn_mfma_f32_16x16x32_bf16(a, b1, z, 0, 0, 0);
            acc[2] = __builtin_amdgcn_mfma_f32_16x16x32_bf16(a, b2, z, 0, 0, 0);
            acc[3] = __builtin_amdgcn_mfma_f32_16x16x32_bf16(a, b3, z, 0, 0, 0);
        }
        {
            bf16x8 b4 = *(const bf16x8*)(w4p + 4 * 512);
            bf16x8 b5 = *(const bf16x8*)(w4p + 5 * 512);
            bf16x8 b6 = *(const bf16x8*)(w4p + 6 * 512);
            bf16x8 b7 = *(const bf16x8*)(w4p + 7 * 512);
            PIN4(b4, b5, b6, b7);
            f32x4 z = {0.f, 0.f, 0.f, 0.f};
            acc[4] = __builtin_amdgcn_mfma_f32_16x16x32_bf16(a, b4, z, 0, 0, 0);
            acc[5] = __builtin_amdgcn_mfma_f32_16x16x32_bf16(a, b5, z, 0, 0, 0);
            acc[6] = __builtin_amdgcn_mfma_f32_16x16x32_bf16(a, b6, z, 0, 0, 0);
            acc[7] = __builtin_amdgcn_mfma_f32_16x16x32_bf16(a, b7, z, 0, 0, 0);
        }
        // tiles: 0,1=Q | 2,3=K | 4,5=V | 6,7=G ; lane cols nl and 16+nl
        const float bg0 = bg[nl], bg1 = bg[16 + nl];
        float kv0 = 0.f, kv1 = 0.f;
        #pragma unroll
        for (int reg = 0; reg < 4; ++reg) {
            float q0 = acc[0][reg], q1 = acc[1][reg];
            float k0 = acc[2][reg], k1 = acc[3][reg];
            float q2 = rowsum16(q0 * q0 + q1 * q1);      // sum over 32 cols
            float k2 = rowsum16(k0 * k0 + k1 * k1);
            float qi = 1.0f / fmaxf(sqrtf(q2), 1e-12f);
            float ki = 1.0f / fmaxf(sqrtf(k2), 1e-12f);
            float g0 = sigmoidf_(acc[6][reg] + bg0);
            float g1 = sigmoidf_(acc[7][reg] + bg1);
            qg0[reg] = q0 * qi * g0;
            qg1[reg] = q1 * qi * g1;
            int rowg = mi2 * 16 + quad * 4 + reg;
            float msk = (rowg < CC) ? 1.0f : 0.0f;
            kv0 += msk * (k0 * ki * acc[4][reg]);
            kv1 += msk * (k1 * ki * acc[5][reg]);
        }
        kv0 += __shfl_xor(kv0, 16); kv0 += __shfl_xor(kv0, 32);
        kv1 += __shfl_xor(kv1, 16); kv1 += __shfl_xor(kv1, 32);
        if (quad == 0) {
            gfp[mi2 * 32 + nl]      = kv0;
            gfp[mi2 * 32 + 16 + nl] = kv1;
        }
    } else {
        const int half = w >> 1;     // waves 1,3 split K over two halves
        float p0 = 0.f, p1 = 0.f;
        #define DN1_STEP(WV, KB)                                              \
        {                                                                     \
            f32x4 c0 = *(const f32x4*)(sh_cv + (KB) * 8);                     \
            f32x4 c1 = *(const f32x4*)(sh_cv + (KB) * 8 + 4);                 \
            p0 += bf2f_s((WV)[0]) * c0[0] + bf2f_s((WV)[1]) * c0[1]           \
                + bf2f_s((WV)[2]) * c0[2] + bf2f_s((WV)[3]) * c0[3];          \
            p1 += bf2f_s((WV)[4]) * c1[0] + bf2f_s((WV)[5]) * c1[1]           \
                + bf2f_s((WV)[6]) * c1[2] + bf2f_s((WV)[7]) * c1[3];          \
        }
        #pragma unroll
        for (int bb = 0; bb < 2; ++bb) {
            const int kb0 = half * 16 + bb * 8;
            const short* dp = dn1P + ((size_t)kb0 * 64 + lane) * 8;
            bf16x8 w0 = *(const bf16x8*)(dp + 0 * 512);
            bf16x8 w1 = *(const bf16x8*)(dp + 1 * 512);
            bf16x8 w2 = *(const bf16x8*)(dp + 2 * 512);
            bf16x8 w3 = *(const bf16x8*)(dp + 3 * 512);
            bf16x8 w4 = *(const bf16x8*)(dp + 4 * 512);
            bf16x8 w5 = *(const bf16x8*)(dp + 5 * 512);
            bf16x8 w6 = *(const bf16x8*)(dp + 6 * 512);
            bf16x8 w7 = *(const bf16x8*)(dp + 7 * 512);
            PIN8(w0, w1, w2, w3, w4, w5, w6, w7);
            DN1_STEP(w0, kb0 + 0) DN1_STEP(w1, kb0 + 1)
            DN1_STEP(w2, kb0 + 2) DN1_STEP(w3, kb0 + 3)
            DN1_STEP(w4, kb0 + 4) DN1_STEP(w5, kb0 + 5)
            DN1_STEP(w6, kb0 + 6) DN1_STEP(w7, kb0 + 7)
        }
        #undef DN1_STEP
        dn1p[half * 64 + lane] = p0 + p1;
    }
    __syncthreads();   // B3

    // ---- Phase 4: finalize h1 and global_feat ------------------------------
    if (t < HH) sh_h1[t] = gelu_exact(dn1p[t] + dn1p[64 + t] + dn1b[t]);
    if (t < RR) sh_gf[t] = gfp[t] + gfp[32 + t];
    __syncthreads();   // B4

    // ---- Phase 5: adaptive gate (dn2, 2x4 group-loaded) + write M ----------
    {
        const float eps = eps_p[0];
        float a0 = 0.f, a1 = 0.f;
        const short* dp = dn2P + (size_t)t * 8;
        #define DN2_STEP(WV, JB)                                              \
        {                                                                     \
            f32x4 h0 = *(const f32x4*)(sh_h1 + (JB) * 8);                     \
            f32x4 h1 = *(const f32x4*)(sh_h1 + (JB) * 8 + 4);                 \
            a0 += bf2f_s((WV)[0]) * h0[0] + bf2f_s((WV)[1]) * h0[1]           \
                + bf2f_s((WV)[2]) * h0[2] + bf2f_s((WV)[3]) * h0[3];          \
            a1 += bf2f_s((WV)[4]) * h1[0] + bf2f_s((WV)[5]) * h1[1]           \
                + bf2f_s((WV)[6]) * h1[2] + bf2f_s((WV)[7]) * h1[3];          \
        }
        {
            bf16x8 d0 = *(const bf16x8*)(dp + 0 * 2048);
            bf16x8 d1 = *(const bf16x8*)(dp + 1 * 2048);
            bf16x8 d2 = *(const bf16x8*)(dp + 2 * 2048);
            bf16x8 d3 = *(const bf16x8*)(dp + 3 * 2048);
            PIN4(d0, d1, d2, d3);
            DN2_STEP(d0, 0) DN2_STEP(d1, 1) DN2_STEP(d2, 2) DN2_STEP(d3, 3)
        }
        {
            bf16x8 d4 = *(const bf16x8*)(dp + 4 * 2048);
            bf16x8 d5 = *(const bf16x8*)(dp + 5 * 2048);
            bf16x8 d6 = *(const bf16x8*)(dp + 6 * 2048);
            bf16x8 d7 = *(const bf16x8*)(dp + 7 * 2048);
            PIN4(d4, d5, d6, d7);
            DN2_STEP(d4, 4) DN2_STEP(d5, 5) DN2_STEP(d6, 6) DN2_STEP(d7, 7)
        }
        #undef DN2_STEP
        sh_gate[t] = sigmoidf_(logits[t] + eps * (a0 + a1 + dn2b[t]));
    }
    if ((w & 1) == 0) {              // M = (Qn*gate_c)*gf, to lowbf[c][r]
        float gf0 = sh_gf[nl], gf1 = sh_gf[16 + nl];
        #pragma unroll
        for (int reg = 0; reg < 4; ++reg) {
            int rowg = mi2 * 16 + quad * 4 + reg;
            lowbf[rowg * LWS + nl]      = f2bf(qg0[reg] * gf0);
            lowbf[rowg * LWS + 16 + nl] = f2bf(qg1[reg] * gf1);
        }
    }
    __syncthreads();   // B5

    // ---- Phase 6: up-proj operand-swapped: C[d][c] = Wu^T @ M^T ------------
    // wave w owns d-tiles w*4..w*4+3, both c-tiles; reg axis = 4 consecutive d
    {
        bf16x8 bf0 = *(const bf16x8*)(lowbf + nl * LWS + quad * 8);        // c=nl
        bf16x8 bf1 = *(const bf16x8*)(lowbf + (16 + nl) * LWS + quad * 8); // c=16+nl
        const int c0 = nl, c1 = 16 + nl;
        const short* wup = WuB + (size_t)(w * 4) * 512 + lane * 8;
        bf16x8 af0 = *(const bf16x8*)(wup + 0 * 512);
        bf16x8 af1 = *(const bf16x8*)(wup + 1 * 512);
        bf16x8 af2 = *(const bf16x8*)(wup + 2 * 512);
        bf16x8 af3 = *(const bf16x8*)(wup + 3 * 512);
        PIN4(af0, af1, af2, af3);
        #define P6_TILE(AF, I)                                                \
        {                                                                     \
            const int dt = w * 4 + (I);                                       \
            f32x4 z = {0.f, 0.f, 0.f, 0.f};                                   \
            f32x4 a0 = __builtin_amdgcn_mfma_f32_16x16x32_bf16(AF, bf0, z, 0, 0, 0); \
            f32x4 a1 = __builtin_amdgcn_mfma_f32_16x16x32_bf16(AF, bf1, z, 0, 0, 0); \
            const int db = dt * 16 + quad * 4;                                \
            const f32x4 gd  = *(const f32x4*)(sh_gate + db);                  \
            const f32x4 bud = *(const f32x4*)(bu + db);                       \
            {                                                                 \
                u16x4 h4 = *(const u16x4*)(hbf + c0 * HBS + db);              \
                f32x4 o;                                                      \
                _Pragma("unroll")                                             \
                for (int reg = 0; reg < 4; ++reg)                             \
                    o[reg] = fmaf(gd[reg], a0[reg] + bud[reg],                \
                                  bf2f_s((short)h4[reg]));                    \
                *(f32x4*)(obase + (size_t)c0 * PD + db) = o;                  \
            }                                                                 \
            if (nl < CC - 16) {                                               \
                u16x4 h4 = *(const u16x4*)(hbf + c1 * HBS + db);              \
                f32x4 o;                                                      \
                _Pragma("unroll")                                             \
                for (int reg = 0; reg < 4; ++reg)                             \
                    o[reg] = fmaf(gd[reg], a1[reg] + bud[reg],                \
                                  bf2f_s((short)h4[reg]));                    \
                *(f32x4*)(obase + (size_t)c1 * PD + db) = o;                  \
            }                                                                 \
        }
        P6_TILE(af0, 0) P6_TILE(af1, 1) P6_TILE(af2, 2) P6_TILE(af3, 3)
        #undef P6_TILE
    }
}

extern "C" void kernel_launch(void* const* d_in, const int* in_sizes, int n_in,
                              void* d_out, int out_size, void* d_ws, size_t ws_size,
                              hipStream_t stream) {
    const float* x    = (const float*)d_in[0];
    const float* ln_w = (const float*)d_in[1];
    const float* ln_b = (const float*)d_in[2];
    const float* Wd   = (const float*)d_in[3];
    const float* bd   = (const float*)d_in[4];
    const float* Wq   = (const float*)d_in[5];
    const float* Wk   = (const float*)d_in[6];
    const float* Wv   = (const float*)d_in[7];
    const float* Wg   = (const float*)d_in[8];
    const float* bg   = (const float*)d_in[9];
    const float* Wu   = (const float*)d_in[10];
    const float* bu   = (const float*)d_in[11];
    const float* cn1w = (const float*)d_in[12];
    const float* cn1b = (const float*)d_in[13];
    const float* cn2w = (const float*)d_in[14];
    const float* cn2b = (const float*)d_in[15];
    const float* dn1w = (const float*)d_in[16];
    const float* dn1b = (const float*)d_in[17];
    const float* dn2w = (const float*)d_in[18];
    const float* dn2b = (const float*)d_in[19];
    const float* eps  = (const float*)d_in[20];
    float* out = (float*)d_out;

    char* ws = (char*)d_ws;
    short* WdB  = (short*)(ws + WS_WDB);
    short* W4B  = (short*)(ws + WS_W4B);
    short* WuB  = (short*)(ws + WS_WUB);
    short* dn1P = (short*)(ws + WS_DN1P);
    short* dn2P = (short*)(ws + WS_DN2P);
    float* s1p  = (float*)(ws + WS_S1);
    float* s2p  = (float*)(ws + WS_S2);
    float* lg   = (float*)(ws + WS_LG);

    hydra_preproc<<<27, NT, 0, stream>>>(ln_w, ln_b, Wd, bd, Wq, Wk, Wv, Wg, Wu,
                                         cn1w, cn1b, cn2w, cn2b, dn1w, dn2w,
                                         WdB, W4B, WuB, dn1P, dn2P, s1p, s2p, lg);
    hydra_fused<<<NBP, NT, 0, stream>>>(x, bg, bu, dn1b, dn2b, eps,
                                        WdB, W4B, WuB, dn1P, dn2P, s1p, s2p, lg,
                                        out);
}

// Round 10
// 316.007 us; speedup vs baseline: 1.0951x; 1.0773x over previous
//
#include <hip/hip_runtime.h>
#include <math.h>

// HydraChannelMixer, MI355X (gfx950). Round 12: 2 bp-rows per block.
// R10 stagger NULL, R11 pins NULL (VGPR stuck at 32 under the 8-blk/CU
// 64-VGPR cap => per-wave latency chains can't be overlapped; waves stall
// ~94% of lifetime). Restructure: each block processes 2 bp-rows through the
// same 5-barrier pipeline (row-unrolled per phase):
// - weight frags (WdB/W4B/dn1P/dn2P/WuB) loaded ONCE, used for both rows
// - barrier/phase-latency cost per row halved; 2x per-wave ILP per phase
// - LDS 34.2KB -> 4 blk/CU -> VGPR cap 128 (was 64): real MLP headroom
// Resident rows/CU unchanged (4x2 vs 8x1). Pins/NT dropped (null/harmful).
// Shapes: B=64, C=21, P=96, D=256, R=32, H=64. Grid = 3072.

#define DD 256
#define CC 21
#define RR 32
#define HH 64
#define PP 96
#define BB 64
#define PD (PP * DD)
#define NBP (BB * PP)     // 6144
#define NT 256

#define HBS 264           // hbf row stride (shorts): 528B, multiple of 16B
#define LWS 40            // lowbf row stride (shorts): 80B, multiple of 16B
#define HROW (CC * HBS)   // per-bp hbf block (shorts)
#define LROW (32 * LWS)   // per-bp lowbf block (shorts)

// d_ws layout (bytes) — identical to proven baseline
#define WS_WDB  0         // 8192 sh: Wd' bf16 frags, 16 tiles (kb*2+ni)*512
#define WS_W4B  16384     // 4096 sh: [Wq|Wk|Wv|Wg] bf16 frags, 8 tiles
#define WS_WUB  24576     // 8192 sh: Wu bf16 frags, 16 tiles
#define WS_DN1P 40960     // 16384 sh: dn1w^T packed bf16 [kb][j][8]
#define WS_DN2P 73728     // 16384 sh: dn2w packed bf16 [jb][d][8]
#define WS_S1   106496    // 32 f32: sum_k bf16(ln_w*Wd)[k][r]
#define WS_S2   106624    // 32 f32: ln_b@Wd + bd
#define WS_LG   106752    // 256 f32: channel_logits

typedef __attribute__((ext_vector_type(8))) short bf16x8;
typedef __attribute__((ext_vector_type(4))) float f32x4;
typedef __attribute__((ext_vector_type(4))) unsigned short u16x4;

__device__ __forceinline__ float gelu_exact(float x) {
    return 0.5f * x * (1.0f + erff(x * 0.70710678118654752440f));
}
__device__ __forceinline__ float sigmoidf_(float x) {
    return 1.0f / (1.0f + __expf(-x));
}
__device__ __forceinline__ short f2bf(float f) {            // RNE f32->bf16
    union { float f; unsigned u; } v; v.f = f;
    unsigned r = v.u + 0x7FFFu + ((v.u >> 16) & 1u);
    return (short)(unsigned short)(r >> 16);
}
__device__ __forceinline__ float bf2f_s(short s) {
    union { unsigned u; float f; } v; v.u = ((unsigned)(unsigned short)s) << 16;
    return v.f;
}

// DPP butterfly add: runs on VALU pipe (not LDS), ~2cyc issue each.
#define DPP_ADD(v, ctrl)                                                      \
    (v) += __builtin_bit_cast(float, __builtin_amdgcn_update_dpp(             \
               0, __builtin_bit_cast(int, (v)), (ctrl), 0xF, 0xF, true))

// all-lane sum over each contiguous 16-lane row: xor1, xor2, ror4, ror8
__device__ __forceinline__ float rowsum16(float v) {
    DPP_ADD(v, 0xB1);   // quad_perm(1,0,3,2) = xor1
    DPP_ADD(v, 0x4E);   // quad_perm(2,3,0,1) = xor2
    DPP_ADD(v, 0x124);  // row_ror:4
    DPP_ADD(v, 0x128);  // row_ror:8
    return v;
}
__device__ __forceinline__ float rdlane(float v, int l) {
    return __builtin_bit_cast(float,
        __builtin_amdgcn_readlane(__builtin_bit_cast(int, v), l));
}

// ---------------------------------------------------------------------------
// Preprocess (27 blocks) — IDENTICAL to proven baseline.
// MFMA frag layout (16x16x32): lane l holds elem[k=(l>>4)*8+j][idx16=l&15];
// this serves as A-frag (idx16=m) or B-frag (idx16=n) interchangeably.
// ---------------------------------------------------------------------------
extern "C" __global__ __launch_bounds__(NT)
void hydra_preproc(const float* __restrict__ ln_w, const float* __restrict__ ln_b,
                   const float* __restrict__ Wd,   const float* __restrict__ bd,
                   const float* __restrict__ Wq,   const float* __restrict__ Wk,
                   const float* __restrict__ Wv,   const float* __restrict__ Wg,
                   const float* __restrict__ Wu,
                   const float* __restrict__ cn1w, const float* __restrict__ cn1b,
                   const float* __restrict__ cn2w, const float* __restrict__ cn2b,
                   const float* __restrict__ dn1w, const float* __restrict__ dn2w,
                   short* __restrict__ WdB, short* __restrict__ W4B,
                   short* __restrict__ WuB, short* __restrict__ dn1P,
                   short* __restrict__ dn2P,
                   float* __restrict__ s1p, float* __restrict__ s2p,
                   float* __restrict__ logits)
{
    const int t = threadIdx.x, lane = t & 63, w = t >> 6, bid = blockIdx.x;
    const int q = lane >> 4, nl = lane & 15;

    if (bid < 4) {                       // WdB: 16 tiles, tile = kb*2 + ni
        int tile = bid * 4 + w;
        int kb = tile >> 1, ni = tile & 1;
        int kbase = kb * 32 + q * 8;
        int n = ni * 16 + nl;
        bf16x8 o;
        #pragma unroll
        for (int j = 0; j < 8; ++j) {
            int k = kbase + j;
            o[j] = f2bf(ln_w[k] * Wd[k * RR + n]);
        }
        *(bf16x8*)(WdB + tile * 512 + lane * 8) = o;
    } else if (bid < 6) {                // W4B: 8 tiles
        int ni = (bid - 4) * 4 + w;
        int n = ni * 16 + nl;
        const float* Wsel = (n < 32) ? Wq : (n < 64) ? Wk : (n < 96) ? Wv : Wg;
        int nn = n & 31;
        bf16x8 o;
        #pragma unroll
        for (int j = 0; j < 8; ++j) o[j] = f2bf(Wsel[(q * 8 + j) * RR + nn]);
        *(bf16x8*)(W4B + ni * 512 + lane * 8) = o;
    } else if (bid < 10) {               // WuB: 16 tiles
        int ni = (bid - 6) * 4 + w;
        int n = ni * 16 + nl;
        bf16x8 o;
        #pragma unroll
        for (int j = 0; j < 8; ++j) o[j] = f2bf(Wu[(q * 8 + j) * DD + n]);
        *(bf16x8*)(WuB + ni * 512 + lane * 8) = o;
    } else if (bid == 10) {              // s1, s2, channel logits
        __shared__ float red1[8][33], red2[8][33];
        __shared__ float clh[HH];
        int r = t & 31, ks = t >> 5;
        float a1 = 0.f, a2 = 0.f;
        for (int k = ks * 32; k < ks * 32 + 32; ++k) {
            float wv = Wd[k * RR + r];
            a1 += bf2f_s(f2bf(ln_w[k] * wv));   // match MFMA's bf16-rounded tile
            a2 += ln_b[k] * wv;
        }
        red1[ks][r] = a1; red2[ks][r] = a2;
        if (t < HH) {
            const float lc = 0.44073977f;       // log(21)/log(1000)
            clh[t] = gelu_exact(lc * cn1w[t] + cn1b[t]);
        }
        __syncthreads();
        if (t < RR) {
            float s1 = 0.f, s2 = 0.f;
            #pragma unroll
            for (int s = 0; s < 8; ++s) { s1 += red1[s][t]; s2 += red2[s][t]; }
            s1p[t] = s1;
            s2p[t] = s2 + bd[t];
        }
        float a = 0.f;
        #pragma unroll 8
        for (int j = 0; j < HH; ++j) a += clh[j] * cn2w[j * DD + t];
        logits[t] = a + cn2b[t];
    } else if (bid < 19) {               // dn1P: [kb][j][8], kb=0..31, j=0..63
        int slot = (bid - 11) * 256 + t; // 0..2047
        int kb = slot >> 6, j = slot & 63;
        bf16x8 o;
        #pragma unroll
        for (int ki = 0; ki < 8; ++ki) o[ki] = f2bf(dn1w[(kb * 8 + ki) * HH + j]);
        *(bf16x8*)(dn1P + slot * 8) = o;
    } else {                             // dn2P: [jb][d][8], jb=0..7, d=0..255
        int slot = (bid - 19) * 256 + t;
        int jb = slot >> 8, d = slot & 255;
        bf16x8 o;
        #pragma unroll
        for (int ji = 0; ji < 8; ++ji) o[ji] = f2bf(dn2w[(jb * 8 + ji) * DD + d]);
        *(bf16x8*)(dn2P + slot * 8) = o;
    }
}

// ---------------------------------------------------------------------------
// Main fused kernel: one block per 2 bp-rows, 256 threads (4 waves),
// 5 barriers. __launch_bounds__(256,4): 4 blocks/CU, VGPR cap 128,
// LDS 34.2KB/block (136.8KB/CU).
// ---------------------------------------------------------------------------
extern "C" __global__ __launch_bounds__(NT, 4)
void hydra_fused(const float* __restrict__ x,
                 const float* __restrict__ bg,   const float* __restrict__ bu,
                 const float* __restrict__ dn1b, const float* __restrict__ dn2b,
                 const float* __restrict__ eps_p,
                 const short* __restrict__ WdB,  const short* __restrict__ W4B,
                 const short* __restrict__ WuB,  const short* __restrict__ dn1P,
                 const short* __restrict__ dn2P,
                 const float* __restrict__ s1p,  const float* __restrict__ s2p,
                 const float* __restrict__ logits,
                 float* __restrict__ out)
{
    __shared__ __align__(16) short  hbf[2 * HROW];    // 22,176 B
    __shared__ __align__(16) short  lowbf[2 * LROW];  //  5,120 B
    __shared__ __align__(16) float  sh_cv[2 * DD];    //  2,048 B
    __shared__ __align__(16) float2 murs[2 * 32];     //    512 B
    __shared__ __align__(16) float  dn1p[2 * 128];    //  1,024 B
    __shared__ __align__(16) float  sh_h1[2 * HH];    //    512 B
    __shared__ __align__(16) float  gfp[2 * 64];      //    512 B
    __shared__ __align__(16) float  sh_gf[2 * RR];    //    256 B
    __shared__ __align__(16) float  sh_gate[2 * DD];  //  2,048 B

    const int t    = threadIdx.x;
    const int lane = t & 63;
    const int w    = t >> 6;
    const int quad = lane >> 4;
    const int nl   = lane & 15;
    const int bp0  = blockIdx.x * 2;

    const float* xb[2];
    float*       ob[2];
    #pragma unroll
    for (int r = 0; r < 2; ++r) {
        int bp = bp0 + r;
        int b  = bp / PP;
        int p  = bp - b * PP;
        xb[r] = x   + (size_t)b * CC * PD + (size_t)p * DD;
        ob[r] = out + (size_t)b * CC * PD + (size_t)p * DD;
    }

    // ---- Phase 1: both rows: load h tile (wave w owns row iter*4+w), bf16
    //      to LDS, LN stats per row via DPP butterflies ----------------------
    #pragma unroll
    for (int r = 0; r < 2; ++r) {
        #pragma unroll
        for (int iter = 0; iter < 6; ++iter) {
            int c = iter * 4 + w;
            bool act = (c < CC);
            f32x4 v = {0.f, 0.f, 0.f, 0.f};
            if (act) v = *(const f32x4*)(xb[r] + (size_t)c * PD + lane * 4);
            if (act) {
                u16x4 u;
                u[0] = (unsigned short)f2bf(v[0]); u[1] = (unsigned short)f2bf(v[1]);
                u[2] = (unsigned short)f2bf(v[2]); u[3] = (unsigned short)f2bf(v[3]);
                *(u16x4*)(hbf + r * HROW + c * HBS + lane * 4) = u;
            }
            float s  = v[0] + v[1] + v[2] + v[3];
            float s2 = v[0]*v[0] + v[1]*v[1] + v[2]*v[2] + v[3]*v[3];
            s  = rowsum16(s);
            s2 = rowsum16(s2);
            float tot  = rdlane(s, 0)  + rdlane(s, 16)  + rdlane(s, 32)  + rdlane(s, 48);
            float tot2 = rdlane(s2, 0) + rdlane(s2, 16) + rdlane(s2, 32) + rdlane(s2, 48);
            if (act && lane == 0) {
                float mu  = tot * (1.0f / DD);
                float var = tot2 * (1.0f / DD) - mu * mu;    // biased (LN)
                murs[r * 32 + c] = make_float2(mu, rsqrtf(var + 1e-5f));
            }
        }
    }
    __syncthreads();   // B1

    // ---- Phase 2: both rows: channel variance + down-proj MFMA -------------
    #pragma unroll
    for (int r = 0; r < 2; ++r) {
        float cs = 0.f, cs2 = 0.f;
        #pragma unroll
        for (int c = 0; c < CC; ++c) {
            float v = bf2f_s(hbf[r * HROW + c * HBS + t]);
            cs += v; cs2 = fmaf(v, v, cs2);
        }
        sh_cv[r * DD + t] = (cs2 - cs * cs * (1.0f / CC)) * (1.0f / (CC - 1));
    }
    {   // wave w: r-tile mt = w&1, c-tile ct = w>>1; weight frags shared rows
        const int mt = w & 1, ct = w >> 1;
        const int c  = ct * 16 + nl;
        const int c_rd = (c < CC) ? c : (CC - 1);    // cols>=21: clone ch 20
        const int r0 = mt * 16 + quad * 4;
        bf16x8 aw[8];
        #pragma unroll
        for (int kb = 0; kb < 8; ++kb)
            aw[kb] = *(const bf16x8*)(WdB + (kb * 2 + mt) * 512 + lane * 8);
        const f32x4 s1v = *(const f32x4*)(s1p + r0);
        const f32x4 s2v = *(const f32x4*)(s2p + r0);
        #pragma unroll
        for (int r = 0; r < 2; ++r) {
            const short* hrow = hbf + r * HROW + c_rd * HBS + quad * 8;
            f32x4 acc = {0.f, 0.f, 0.f, 0.f};
            #pragma unroll
            for (int kb = 0; kb < 8; ++kb)
                acc = __builtin_amdgcn_mfma_f32_16x16x32_bf16(
                          aw[kb], *(const bf16x8*)(hrow + kb * 32), acc, 0, 0, 0);
            const float2 mr = murs[r * 32 + c_rd];
            u16x4 o;
            #pragma unroll
            for (int reg = 0; reg < 4; ++reg)
                o[reg] = (unsigned short)f2bf(
                    mr.y * (acc[reg] - mr.x * s1v[reg]) + s2v[reg]);
            *(u16x4*)(lowbf + r * LROW + c * LWS + r0) = o;
        }
    }
    __syncthreads();   // B2

    // ---- Phase 3: waves 0,2: QKVG MFMA both rows (W4B frags shared) +
    //               norms + gate + KV pool; waves 1,3: dn1 both rows ---------
    const int mi2 = w >> 1;
    float qga[2][4], qgb[2][4];
    if ((w & 1) == 0) {
        bf16x8 bfr[8];
        #pragma unroll
        for (int i = 0; i < 8; ++i)
            bfr[i] = *(const bf16x8*)(W4B + i * 512 + lane * 8);
        const float bg0 = bg[nl], bg1 = bg[16 + nl];
        const int m = mi2 * 16 + nl;
        #pragma unroll
        for (int r = 0; r < 2; ++r) {
            bf16x8 a = *(const bf16x8*)(lowbf + r * LROW + m * LWS + quad * 8);
            f32x4 acc[8];
            #pragma unroll
            for (int i = 0; i < 8; ++i) {
                f32x4 z = {0.f, 0.f, 0.f, 0.f};
                acc[i] = __builtin_amdgcn_mfma_f32_16x16x32_bf16(a, bfr[i], z, 0, 0, 0);
            }
            // tiles: 0,1=Q | 2,3=K | 4,5=V | 6,7=G ; lane cols nl and 16+nl
            float kv0 = 0.f, kv1 = 0.f;
            #pragma unroll
            for (int reg = 0; reg < 4; ++reg) {
                float q0 = acc[0][reg], q1 = acc[1][reg];
                float k0 = acc[2][reg], k1 = acc[3][reg];
                float q2 = rowsum16(q0 * q0 + q1 * q1);      // sum over 32 cols
                float k2 = rowsum16(k0 * k0 + k1 * k1);
                float qi = 1.0f / fmaxf(sqrtf(q2), 1e-12f);
                float ki = 1.0f / fmaxf(sqrtf(k2), 1e-12f);
                float g0 = sigmoidf_(acc[6][reg] + bg0);
                float g1 = sigmoidf_(acc[7][reg] + bg1);
                qga[r][reg] = q0 * qi * g0;
                qgb[r][reg] = q1 * qi * g1;
                int rowg = mi2 * 16 + quad * 4 + reg;
                float msk = (rowg < CC) ? 1.0f : 0.0f;
                kv0 += msk * (k0 * ki * acc[4][reg]);
                kv1 += msk * (k1 * ki * acc[5][reg]);
            }
            kv0 += __shfl_xor(kv0, 16); kv0 += __shfl_xor(kv0, 32);
            kv1 += __shfl_xor(kv1, 16); kv1 += __shfl_xor(kv1, 32);
            if (quad == 0) {
                gfp[r * 64 + mi2 * 32 + nl]      = kv0;
                gfp[r * 64 + mi2 * 32 + 16 + nl] = kv1;
            }
        }
    } else {
        const int half = w >> 1;     // waves 1,3 split K over two halves
        float p0a = 0.f, p1a = 0.f, p0b = 0.f, p1b = 0.f;
        #pragma unroll
        for (int i = 0; i < 16; ++i) {
            int kb = half * 16 + i;
            bf16x8 wv = *(const bf16x8*)(dn1P + ((size_t)kb * 64 + lane) * 8);
            f32x4 c0a = *(const f32x4*)(sh_cv + 0 * DD + kb * 8);
            f32x4 c1a = *(const f32x4*)(sh_cv + 0 * DD + kb * 8 + 4);
            f32x4 c0b = *(const f32x4*)(sh_cv + 1 * DD + kb * 8);
            f32x4 c1b = *(const f32x4*)(sh_cv + 1 * DD + kb * 8 + 4);
            float w0 = bf2f_s(wv[0]), w1 = bf2f_s(wv[1]), w2 = bf2f_s(wv[2]), w3 = bf2f_s(wv[3]);
            float w4 = bf2f_s(wv[4]), w5 = bf2f_s(wv[5]), w6 = bf2f_s(wv[6]), w7 = bf2f_s(wv[7]);
            p0a += w0 * c0a[0] + w1 * c0a[1] + w2 * c0a[2] + w3 * c0a[3];
            p1a += w4 * c1a[0] + w5 * c1a[1] + w6 * c1a[2] + w7 * c1a[3];
            p0b += w0 * c0b[0] + w1 * c0b[1] + w2 * c0b[2] + w3 * c0b[3];
            p1b += w4 * c1b[0] + w5 * c1b[1] + w6 * c1b[2] + w7 * c1b[3];
        }
        dn1p[0 * 128 + half * 64 + lane] = p0a + p1a;
        dn1p[1 * 128 + half * 64 + lane] = p0b + p1b;
    }
    __syncthreads();   // B3

    // ---- Phase 4: finalize h1 and global_feat (both rows, split threads) ---
    if (t < 2 * HH) {
        int r = t >> 6, j = t & 63;
        sh_h1[r * HH + j] = gelu_exact(dn1p[r * 128 + j] + dn1p[r * 128 + 64 + j]
                                       + dn1b[j]);
    }
    if (t < 2 * RR) {
        int r = t >> 5, j = t & 31;
        sh_gf[r * RR + j] = gfp[r * 64 + j] + gfp[r * 64 + 32 + j];
    }
    __syncthreads();   // B4

    // ---- Phase 5: adaptive gate (dn2 frags shared rows) + write M ----------
    {
        const float eps = eps_p[0];
        float a0a = 0.f, a1a = 0.f, a0b = 0.f, a1b = 0.f;
        #pragma unroll
        for (int jb = 0; jb < 8; ++jb) {
            bf16x8 wv = *(const bf16x8*)(dn2P + ((size_t)jb * 256 + t) * 8);
            f32x4 h0a = *(const f32x4*)(sh_h1 + 0 * HH + jb * 8);
            f32x4 h1a = *(const f32x4*)(sh_h1 + 0 * HH + jb * 8 + 4);
            f32x4 h0b = *(const f32x4*)(sh_h1 + 1 * HH + jb * 8);
            f32x4 h1b = *(const f32x4*)(sh_h1 + 1 * HH + jb * 8 + 4);
            float w0 = bf2f_s(wv[0]), w1 = bf2f_s(wv[1]), w2 = bf2f_s(wv[2]), w3 = bf2f_s(wv[3]);
            float w4 = bf2f_s(wv[4]), w5 = bf2f_s(wv[5]), w6 = bf2f_s(wv[6]), w7 = bf2f_s(wv[7]);
            a0a += w0 * h0a[0] + w1 * h0a[1] + w2 * h0a[2] + w3 * h0a[3];
            a1a += w4 * h1a[0] + w5 * h1a[1] + w6 * h1a[2] + w7 * h1a[3];
            a0b += w0 * h0b[0] + w1 * h0b[1] + w2 * h0b[2] + w3 * h0b[3];
            a1b += w4 * h1b[0] + w5 * h1b[1] + w6 * h1b[2] + w7 * h1b[3];
        }
        const float lg = logits[t], db2 = dn2b[t];
        sh_gate[0 * DD + t] = sigmoidf_(lg + eps * (a0a + a1a + db2));
        sh_gate[1 * DD + t] = sigmoidf_(lg + eps * (a0b + a1b + db2));
    }
    if ((w & 1) == 0) {              // M = (Qn*gate_c)*gf, to lowbf[r][c][r32]
        #pragma unroll
        for (int r = 0; r < 2; ++r) {
            float gf0 = sh_gf[r * RR + nl], gf1 = sh_gf[r * RR + 16 + nl];
            #pragma unroll
            for (int reg = 0; reg < 4; ++reg) {
                int rowg = mi2 * 16 + quad * 4 + reg;
                lowbf[r * LROW + rowg * LWS + nl]      = f2bf(qga[r][reg] * gf0);
                lowbf[r * LROW + rowg * LWS + 16 + nl] = f2bf(qgb[r][reg] * gf1);
            }
        }
    }
    __syncthreads();   // B5

    // ---- Phase 6: up-proj both rows (WuB frags shared): C[d][c] = Wu^T@M^T -
    {
        bf16x8 af[4];
        #pragma unroll
        for (int i = 0; i < 4; ++i)
            af[i] = *(const bf16x8*)(WuB + (size_t)(w * 4 + i) * 512 + lane * 8);
        const int c0 = nl, c1 = 16 + nl;
        #pragma unroll
        for (int r = 0; r < 2; ++r) {
            bf16x8 bf0 = *(const bf16x8*)(lowbf + r * LROW + nl * LWS + quad * 8);
            bf16x8 bf1 = *(const bf16x8*)(lowbf + r * LROW + (16 + nl) * LWS + quad * 8);
            #pragma unroll
            for (int i = 0; i < 4; ++i) {
                const int dt = w * 4 + i;
                f32x4 z = {0.f, 0.f, 0.f, 0.f};
                f32x4 a0 = __builtin_amdgcn_mfma_f32_16x16x32_bf16(af[i], bf0, z, 0, 0, 0);
                f32x4 a1 = __builtin_amdgcn_mfma_f32_16x16x32_bf16(af[i], bf1, z, 0, 0, 0);
                const int db = dt * 16 + quad * 4;
                const f32x4 gd  = *(const f32x4*)(sh_gate + r * DD + db);
                const f32x4 bud = *(const f32x4*)(bu + db);
                {
                    u16x4 h4 = *(const u16x4*)(hbf + r * HROW + c0 * HBS + db);
                    f32x4 o;
                    #pragma unroll
                    for (int reg = 0; reg < 4; ++reg)
                        o[reg] = fmaf(gd[reg], a0[reg] + bud[reg],
                                      bf2f_s((short)h4[reg]));
                    *(f32x4*)(ob[r] + (size_t)c0 * PD + db) = o;
                }
                if (nl < CC - 16) {      // c1 < 21
                    u16x4 h4 = *(const u16x4*)(hbf + r * HROW + c1 * HBS + db);
                    f32x4 o;
                    #pragma unroll
                    for (int reg = 0; reg < 4; ++reg)
                        o[reg] = fmaf(gd[reg], a1[reg] + bud[reg],
                                      bf2f_s((short)h4[reg]));
                    *(f32x4*)(ob[r] + (size_t)c1 * PD + db) = o;
                }
            }
        }
    }
}

extern "C" void kernel_launch(void* const* d_in, const int* in_sizes, int n_in,
                              void* d_out, int out_size, void* d_ws, size_t ws_size,
                              hipStream_t stream) {
    const float* x    = (const float*)d_in[0];
    const float* ln_w = (const float*)d_in[1];
    const float* ln_b = (const float*)d_in[2];
    const float* Wd   = (const float*)d_in[3];
    const float* bd   = (const float*)d_in[4];
    const float* Wq   = (const float*)d_in[5];
    const float* Wk   = (const float*)d_in[6];
    const float* Wv   = (const float*)d_in[7];
    const float* Wg   = (const float*)d_in[8];
    const float* bg   = (const float*)d_in[9];
    const float* Wu   = (const float*)d_in[10];
    const float* bu   = (const float*)d_in[11];
    const float* cn1w = (const float*)d_in[12];
    const float* cn1b = (const float*)d_in[13];
    const float* cn2w = (const float*)d_in[14];
    const float* cn2b = (const float*)d_in[15];
    const float* dn1w = (const float*)d_in[16];
    const float* dn1b = (const float*)d_in[17];
    const float* dn2w = (const float*)d_in[18];
    const float* dn2b = (const float*)d_in[19];
    const float* eps  = (const float*)d_in[20];
    float* out = (float*)d_out;

    char* ws = (char*)d_ws;
    short* WdB  = (short*)(ws + WS_WDB);
    short* W4B  = (short*)(ws + WS_W4B);
    short* WuB  = (short*)(ws + WS_WUB);
    short* dn1P = (short*)(ws + WS_DN1P);
    short* dn2P = (short*)(ws + WS_DN2P);
    float* s1p  = (float*)(ws + WS_S1);
    float* s2p  = (float*)(ws + WS_S2);
    float* lg   = (float*)(ws + WS_LG);

    hydra_preproc<<<27, NT, 0, stream>>>(ln_w, ln_b, Wd, bd, Wq, Wk, Wv, Wg, Wu,
                                         cn1w, cn1b, cn2w, cn2b, dn1w, dn2w,
                                         WdB, W4B, WuB, dn1P, dn2P, s1p, s2p, lg);
    hydra_fused<<<NBP / 2, NT, 0, stream>>>(x, bg, bu, dn1b, dn2b, eps,
                                            WdB, W4B, WuB, dn1P, dn2P, s1p, s2p, lg,
                                            out);
}